// Round 19
// baseline (47.531 us; speedup 1.0000x reference)
//
#include <hip/hip_runtime.h>

// R17: gather-free. R14/R16 analysis: the 2 random batch[] gathers per edge
// (128 scattered L1/TA lane-transactions per 64-edge group, ~390cy/group on
// the per-CU TA path) are the serialized invisible resource -> every pipeline
// variant stuck at 44-54us. batch is SORTED: replace gathers with a 6-step
// binary search over the 65-entry graph-boundary table staged in LDS.
// M/Dt/MFMA body byte-identical to the twice-verified R10 kernel (absmax 4).

#define NG 64
#define NCOMP 6
#define NPART (NG * NCOMP)      // 384
#define RED1_BLOCKS 64
#define MFMA_BLOCKS 768         // 3 blocks/CU (LDS-capped)
#define WPB 4
#define MROW 72                 // 64 + 8 pad ushorts; 144B rows (16B-aligned)
#define DROW 72

typedef unsigned short u16_t;
typedef unsigned int   u32_t;
typedef __attribute__((ext_vector_type(8))) short short8;
typedef __attribute__((ext_vector_type(4))) float f32x4;

__device__ __forceinline__ u16_t f2bf(float f) {
    union { float f; u32_t u; } v; v.f = f;
    u32_t r = v.u + 0x7FFFu + ((v.u >> 16) & 1u);
    return (u16_t)(r >> 16);
}

__device__ __forceinline__ void lds_add(float* p, float v) {
    __hip_atomic_fetch_add(p, v, __ATOMIC_RELAXED, __HIP_MEMORY_SCOPE_WORKGROUP);
}

// graph(a) = max{g : Bs[g] <= a}; Bs[g] = first atom index with graph >= g
__device__ __forceinline__ int gsearch(const int* Bs, int a) {
    int lo = 0;
#pragma unroll
    for (int st = 32; st >= 1; st >>= 1)
        lo += (Bs[lo + st] <= a) ? st : 0;
    return lo;
}

// ---------------- bounds-table construction ----------------
__global__ void bounds_init(int* __restrict__ B, int N) {
    int i = threadIdx.x;
    if (i < 65) B[i] = N;
}

__global__ __launch_bounds__(256) void bounds_min(
    const int* __restrict__ batch, int* __restrict__ B, int N)
{
    __shared__ int lb[64];
    int t = threadIdx.x;
    if (t < 64) lb[t] = N;
    __syncthreads();
    for (int i = blockIdx.x * blockDim.x + t; i < N; i += gridDim.x * blockDim.x)
        atomicMin(&lb[batch[i]], i);
    __syncthreads();
    if (t < 64 && lb[t] < N) atomicMin(&B[t], lb[t]);
}

__global__ void bounds_fix(int* __restrict__ B) {
    if (threadIdx.x == 0) {
        for (int g = 63; g >= 0; --g)
            if (B[g] > B[g + 1]) B[g] = B[g + 1];
    }
}

// ---------------- MFMA main kernel ----------------
__global__ __launch_bounds__(256) void virial_mfma(
    const float* __restrict__ disp, const float* __restrict__ edge_w,
    const int* __restrict__ edge_index, const int* __restrict__ Bg,
    float* __restrict__ partials, int E)
{
    __shared__ u16_t Msh[WPB][NG * MROW];   // 36864 B
    __shared__ u16_t Dsh[WPB][16 * DROW];   //  9216 B (rows 6..15 stay zero;
                                            //  reused as per-wave f32 stage)
    __shared__ int   Bs[65];                //   260 B graph-boundary table

    const int lane = threadIdx.x & 63;
    const int wave = threadIdx.x >> 6;
    u16_t* Mw = Msh[wave];
    u16_t* Dw = Dsh[wave];

    if (threadIdx.x < 65) Bs[threadIdx.x] = Bg[threadIdx.x];
    {   // zero per-wave M and Dt (same-wave DS ops are in order)
        u32_t* p = (u32_t*)Mw;
        for (int i = lane; i < NG * MROW / 2; i += 64) p[i] = 0u;
        u32_t* q = (u32_t*)Dw;
        for (int i = lane; i < 16 * DROW / 2; i += 64) q[i] = 0u;
    }
    __syncthreads();   // Bs ready (read-only afterwards)

    f32x4 acc0 = {0,0,0,0}, acc1 = {0,0,0,0}, acc2 = {0,0,0,0}, acc3 = {0,0,0,0};
    const int ngroups = (E + 63) >> 6;
    const int gstride = (int)gridDim.x * WPB;
    const int c_l = lane & 15;
    const int k4  = lane >> 4;
    int pg0 = 0, pg1 = 0;

    int grp = (int)blockIdx.x * WPB + wave;

    // 1-deep prefetch of the STREAMING loads (w, disp, idx) — no gathers
    float pw = 0.f, px = 0.f, py = 0.f, pz = 0.f;
    int   ps = 0, pt = 0;
    if (grp < ngroups) {
        int e  = grp * 64 + lane;
        int ec = e < E ? e : E - 1;
        pw = (e < E) ? edge_w[ec] : 0.f;   // w=0 kills clamped-tail terms
        px = disp[ec * 3 + 0];
        py = disp[ec * 3 + 1];
        pz = disp[ec * 3 + 2];
        ps = edge_index[ec];
        pt = edge_index[E + ec];
    }

    while (grp < ngroups) {
        const float w = pw, d0 = px, d1 = py, d2 = pz;
        const int   sC = ps, tC = pt;

        const int nxt = grp + gstride;
        if (nxt < ngroups) {
            int e  = nxt * 64 + lane;
            int ec = e < E ? e : E - 1;
            pw = (e < E) ? edge_w[ec] : 0.f;
            px = disp[ec * 3 + 0];
            py = disp[ec * 3 + 1];
            pz = disp[ec * 3 + 2];
            ps = edge_index[ec];
            pt = edge_index[E + ec];
        }

        // gather-free endpoint->graph: 6-step ladder over LDS table
        const int g0 = gsearch(Bs, sC);
        const int g1 = gsearch(Bs, tC);

        // --- R10-verified body ---
        Mw[pg0 * MROW + lane] = 0;
        Mw[pg1 * MROW + lane] = 0;
        Mw[g0 * MROW + lane] = 0x3F80u;                          // 1.0
        Mw[g1 * MROW + lane] = (g1 == g0) ? 0x4000u : 0x3F80u;   // 2.0 / 1.0
        pg0 = g0; pg1 = g1;

        float cw = -2.f * w;
        Dw[0 * DROW + lane] = f2bf(cw * d0 * d0);
        Dw[1 * DROW + lane] = f2bf(cw * d0 * d1);
        Dw[2 * DROW + lane] = f2bf(cw * d0 * d2);
        Dw[3 * DROW + lane] = f2bf(cw * d1 * d1);
        Dw[4 * DROW + lane] = f2bf(cw * d1 * d2);
        Dw[5 * DROW + lane] = f2bf(cw * d2 * d2);

#pragma unroll
        for (int half = 0; half < 2; ++half) {
            const int kb = half * 32 + k4 * 8;
            short8 bf = *(const short8*)&Dw[c_l * DROW + kb];
            short8 a0 = *(const short8*)&Mw[( 0 + c_l) * MROW + kb];
            short8 a1 = *(const short8*)&Mw[(16 + c_l) * MROW + kb];
            short8 a2 = *(const short8*)&Mw[(32 + c_l) * MROW + kb];
            short8 a3 = *(const short8*)&Mw[(48 + c_l) * MROW + kb];
            acc0 = __builtin_amdgcn_mfma_f32_16x16x32_bf16(a0, bf, acc0, 0, 0, 0);
            acc1 = __builtin_amdgcn_mfma_f32_16x16x32_bf16(a1, bf, acc1, 0, 0, 0);
            acc2 = __builtin_amdgcn_mfma_f32_16x16x32_bf16(a2, bf, acc2, 0, 0, 0);
            acc3 = __builtin_amdgcn_mfma_f32_16x16x32_bf16(a3, bf, acc3, 0, 0, 0);
        }

        grp = nxt;
    }

    // C/D layout: col=lane&15, row=(lane>>4)*4+reg (m89-verified)
    float* Ow = (float*)Dw;   // Dt dead; 2304 B >= 1536 B needed
    if (c_l < NCOMP) {
#pragma unroll
        for (int r = 0; r < 4; ++r) {
            Ow[( 0 + k4 * 4 + r) * NCOMP + c_l] = acc0[r];
            Ow[(16 + k4 * 4 + r) * NCOMP + c_l] = acc1[r];
            Ow[(32 + k4 * 4 + r) * NCOMP + c_l] = acc2[r];
            Ow[(48 + k4 * 4 + r) * NCOMP + c_l] = acc3[r];
        }
    }
    __syncthreads();
    for (int i = threadIdx.x; i < NPART; i += blockDim.x) {
        float s = ((const float*)Dsh[0])[i] + ((const float*)Dsh[1])[i]
                + ((const float*)Dsh[2])[i] + ((const float*)Dsh[3])[i];
        partials[(size_t)blockIdx.x * NPART + i] = s;
    }
}

// ---------------- reductions (atomic-free) ----------------
__global__ __launch_bounds__(NPART) void reduce1_kernel(
    const float* __restrict__ partials, float* __restrict__ partials2, int nblk)
{
    int i = threadIdx.x, j = blockIdx.x;
    float s = 0.f;
    for (int b = j; b < nblk; b += RED1_BLOCKS)
        s += partials[(size_t)b * NPART + i];
    partials2[(size_t)j * NPART + i] = s;
}

__global__ __launch_bounds__(NPART) void reduce2_kernel(
    const float* __restrict__ partials2, float* __restrict__ dst)  // dst: 64*9
{
    int i = threadIdx.x;
    float s = 0.f;
#pragma unroll
    for (int j = 0; j < RED1_BLOCKS; ++j)
        s += partials2[(size_t)j * NPART + i];
    int g = i / NCOMP, c = i % NCOMP;
    int r   = (c < 3) ? 0 : ((c < 5) ? 1 : 2);
    int col = (c < 3) ? c : ((c < 5) ? c - 2 : 2);
    dst[g * 9 + r * 3 + col] = s;
    if (r != col) dst[g * 9 + col * 3 + r] = s;
}

// ---------------- fallback (tiny ws): LDS-atomic path ----------------
__global__ void zero_out_kernel(float* __restrict__ out, int n) {
    int i = blockIdx.x * blockDim.x + threadIdx.x;
    if (i < n) out[i] = 0.f;
}

__global__ __launch_bounds__(256) void virial_atomic(
    const float* __restrict__ disp, const float* __restrict__ edge_w,
    const int* __restrict__ edge_index, const int* __restrict__ batch,
    float* __restrict__ out, int E)
{
    __shared__ float acc[NG * 7];
    for (int i = threadIdx.x; i < NG * 7; i += blockDim.x) acc[i] = 0.f;
    __syncthreads();
    int tid = blockIdx.x * blockDim.x + threadIdx.x;
    int stride = gridDim.x * blockDim.x;
    for (int e = tid; e < E; e += stride) {
        float d0 = disp[e*3], d1 = disp[e*3+1], d2 = disp[e*3+2];
        float c = -2.f * edge_w[e];
        int g0 = batch[edge_index[e]], g1 = batch[edge_index[E + e]];
        float v[6] = {c*d0*d0, c*d0*d1, c*d0*d2, c*d1*d1, c*d1*d2, c*d2*d2};
#pragma unroll
        for (int k = 0; k < 6; ++k) {
            lds_add(&acc[g0*7+k], v[k]);
            lds_add(&acc[g1*7+k], v[k]);
        }
    }
    __syncthreads();
    for (int i = threadIdx.x; i < NG * 9; i += blockDim.x) {
        int g = i / 9, ij = i % 9, r = ij / 3, cc = ij % 3;
        int lo = r < cc ? r : cc, hi = r < cc ? cc : r;
        int comp = (lo == 0) ? hi : ((lo == 1) ? 2 + hi : 5);
        __hip_atomic_fetch_add(&out[i], acc[g*7+comp], __ATOMIC_RELAXED, __HIP_MEMORY_SCOPE_AGENT);
    }
}

extern "C" void kernel_launch(void* const* d_in, const int* in_sizes, int n_in,
                              void* d_out, int out_size, void* d_ws, size_t ws_size,
                              hipStream_t stream) {
    const float* disp       = (const float*)d_in[0];
    const float* edge_w     = (const float*)d_in[1];
    const int*   edge_index = (const int*)d_in[2];
    const int*   batch      = (const int*)d_in[3];
    float*       out        = (float*)d_out;
    const int E = in_sizes[1];
    const int N = in_sizes[3];

    const size_t need = (size_t)(MFMA_BLOCKS + RED1_BLOCKS) * NPART * sizeof(float)
                        + 128 * sizeof(int);

    if (ws_size >= need) {
        float* pm = (float*)d_ws;                         // [MFMA_BLOCKS][NPART]
        float* p2 = pm + (size_t)MFMA_BLOCKS * NPART;     // [RED1_BLOCKS][NPART]
        int*   B  = (int*)(p2 + (size_t)RED1_BLOCKS * NPART);   // [65]

        bounds_init<<<1, 128, 0, stream>>>(B, N);
        bounds_min<<<256, 256, 0, stream>>>(batch, B, N);
        bounds_fix<<<1, 64, 0, stream>>>(B);
        virial_mfma<<<MFMA_BLOCKS, 256, 0, stream>>>(disp, edge_w, edge_index, B, pm, E);
        reduce1_kernel<<<RED1_BLOCKS, NPART, 0, stream>>>(pm, p2, MFMA_BLOCKS);
        reduce2_kernel<<<1, NPART, 0, stream>>>(p2, out);
    } else {
        zero_out_kernel<<<1, 256, 0, stream>>>(out, NG * 9);
        virial_atomic<<<2048, 256, 0, stream>>>(disp, edge_w, edge_index, batch, out, E);
    }
}

// Round 20
// 42.435 us; speedup vs baseline: 1.1201x; 1.1201x over previous
//
#include <hip/hip_runtime.h>

// R20: R19 (gather-free, verified absmax 4) minus the serial bounds_fix
// kernel. R19 readout: main kernel dropped below the 38us fill-dispatch
// floor (gather theory confirmed) but total rose to 47.5 -> the single-
// threaded bounds_fix (64 dependent L2 RMWs ~ 10-12us) ate the gain.
// Now each block suffix-min-scans Bs[65] in its prologue (7 steps, ~100ns).

#define NG 64
#define NCOMP 6
#define NPART (NG * NCOMP)      // 384
#define RED1_BLOCKS 64
#define MFMA_BLOCKS 768         // 3 blocks/CU (LDS-capped)
#define WPB 4
#define MROW 72                 // 64 + 8 pad ushorts; 144B rows (16B-aligned)
#define DROW 72

typedef unsigned short u16_t;
typedef unsigned int   u32_t;
typedef __attribute__((ext_vector_type(8))) short short8;
typedef __attribute__((ext_vector_type(4))) float f32x4;

__device__ __forceinline__ u16_t f2bf(float f) {
    union { float f; u32_t u; } v; v.f = f;
    u32_t r = v.u + 0x7FFFu + ((v.u >> 16) & 1u);
    return (u16_t)(r >> 16);
}

__device__ __forceinline__ void lds_add(float* p, float v) {
    __hip_atomic_fetch_add(p, v, __ATOMIC_RELAXED, __HIP_MEMORY_SCOPE_WORKGROUP);
}

// graph(a) = max{g : Bs[g] <= a}; after suffix-min, Bs[g] = first atom with
// graph >= g (non-decreasing); Bs[64] = N sentinel.
__device__ __forceinline__ int gsearch(const int* Bs, int a) {
    int lo = 0;
#pragma unroll
    for (int st = 32; st >= 1; st >>= 1)
        lo += (Bs[lo + st] <= a) ? st : 0;
    return lo;
}

// ---------------- bounds-table construction ----------------
__global__ void bounds_init(int* __restrict__ B, int N) {
    int i = threadIdx.x;
    if (i < 65) B[i] = N;
}

__global__ __launch_bounds__(256) void bounds_min(
    const int* __restrict__ batch, int* __restrict__ B, int N)
{
    __shared__ int lb[64];
    int t = threadIdx.x;
    if (t < 64) lb[t] = N;
    __syncthreads();
    for (int i = blockIdx.x * blockDim.x + t; i < N; i += gridDim.x * blockDim.x)
        atomicMin(&lb[batch[i]], i);
    __syncthreads();
    if (t < 64 && lb[t] < N) atomicMin(&B[t], lb[t]);
}

// ---------------- MFMA main kernel ----------------
__global__ __launch_bounds__(256) void virial_mfma(
    const float* __restrict__ disp, const float* __restrict__ edge_w,
    const int* __restrict__ edge_index, const int* __restrict__ Bg,
    float* __restrict__ partials, int E)
{
    __shared__ u16_t Msh[WPB][NG * MROW];   // 36864 B
    __shared__ u16_t Dsh[WPB][16 * DROW];   //  9216 B (rows 6..15 stay zero;
                                            //  reused as per-wave f32 stage)
    __shared__ int   Bs[65];                //   260 B graph-boundary table

    const int lane = threadIdx.x & 63;
    const int wave = threadIdx.x >> 6;
    u16_t* Mw = Msh[wave];
    u16_t* Dw = Dsh[wave];

    if (threadIdx.x < 65) Bs[threadIdx.x] = Bg[threadIdx.x];
    {   // zero per-wave M and Dt (same-wave DS ops are in order)
        u32_t* p = (u32_t*)Mw;
        for (int i = lane; i < NG * MROW / 2; i += 64) p[i] = 0u;
        u32_t* q = (u32_t*)Dw;
        for (int i = lane; i < 16 * DROW / 2; i += 64) q[i] = 0u;
    }
    __syncthreads();   // raw Bs loaded

    // in-block suffix-min scan (replaces the serial bounds_fix kernel):
    // Bs[g] <- min(B[g..64])
#pragma unroll
    for (int st = 1; st < 65; st <<= 1) {
        int v = 0;
        const bool act = (threadIdx.x < 65) && (threadIdx.x + st <= 64);
        if (act) v = min(Bs[threadIdx.x], Bs[threadIdx.x + st]);
        __syncthreads();
        if (act) Bs[threadIdx.x] = v;
        __syncthreads();
    }

    f32x4 acc0 = {0,0,0,0}, acc1 = {0,0,0,0}, acc2 = {0,0,0,0}, acc3 = {0,0,0,0};
    const int ngroups = (E + 63) >> 6;
    const int gstride = (int)gridDim.x * WPB;
    const int c_l = lane & 15;
    const int k4  = lane >> 4;
    int pg0 = 0, pg1 = 0;

    int grp = (int)blockIdx.x * WPB + wave;

    // 1-deep prefetch of the STREAMING loads (w, disp, idx) — no gathers
    float pw = 0.f, px = 0.f, py = 0.f, pz = 0.f;
    int   ps = 0, pt = 0;
    if (grp < ngroups) {
        int e  = grp * 64 + lane;
        int ec = e < E ? e : E - 1;
        pw = (e < E) ? edge_w[ec] : 0.f;   // w=0 kills clamped-tail terms
        px = disp[ec * 3 + 0];
        py = disp[ec * 3 + 1];
        pz = disp[ec * 3 + 2];
        ps = edge_index[ec];
        pt = edge_index[E + ec];
    }

    while (grp < ngroups) {
        const float w = pw, d0 = px, d1 = py, d2 = pz;
        const int   sC = ps, tC = pt;

        const int nxt = grp + gstride;
        if (nxt < ngroups) {
            int e  = nxt * 64 + lane;
            int ec = e < E ? e : E - 1;
            pw = (e < E) ? edge_w[ec] : 0.f;
            px = disp[ec * 3 + 0];
            py = disp[ec * 3 + 1];
            pz = disp[ec * 3 + 2];
            ps = edge_index[ec];
            pt = edge_index[E + ec];
        }

        // gather-free endpoint->graph: 6-step ladder over LDS table
        const int g0 = gsearch(Bs, sC);
        const int g1 = gsearch(Bs, tC);

        // --- R10-verified body ---
        Mw[pg0 * MROW + lane] = 0;
        Mw[pg1 * MROW + lane] = 0;
        Mw[g0 * MROW + lane] = 0x3F80u;                          // 1.0
        Mw[g1 * MROW + lane] = (g1 == g0) ? 0x4000u : 0x3F80u;   // 2.0 / 1.0
        pg0 = g0; pg1 = g1;

        float cw = -2.f * w;
        Dw[0 * DROW + lane] = f2bf(cw * d0 * d0);
        Dw[1 * DROW + lane] = f2bf(cw * d0 * d1);
        Dw[2 * DROW + lane] = f2bf(cw * d0 * d2);
        Dw[3 * DROW + lane] = f2bf(cw * d1 * d1);
        Dw[4 * DROW + lane] = f2bf(cw * d1 * d2);
        Dw[5 * DROW + lane] = f2bf(cw * d2 * d2);

#pragma unroll
        for (int half = 0; half < 2; ++half) {
            const int kb = half * 32 + k4 * 8;
            short8 bf = *(const short8*)&Dw[c_l * DROW + kb];
            short8 a0 = *(const short8*)&Mw[( 0 + c_l) * MROW + kb];
            short8 a1 = *(const short8*)&Mw[(16 + c_l) * MROW + kb];
            short8 a2 = *(const short8*)&Mw[(32 + c_l) * MROW + kb];
            short8 a3 = *(const short8*)&Mw[(48 + c_l) * MROW + kb];
            acc0 = __builtin_amdgcn_mfma_f32_16x16x32_bf16(a0, bf, acc0, 0, 0, 0);
            acc1 = __builtin_amdgcn_mfma_f32_16x16x32_bf16(a1, bf, acc1, 0, 0, 0);
            acc2 = __builtin_amdgcn_mfma_f32_16x16x32_bf16(a2, bf, acc2, 0, 0, 0);
            acc3 = __builtin_amdgcn_mfma_f32_16x16x32_bf16(a3, bf, acc3, 0, 0, 0);
        }

        grp = nxt;
    }

    // C/D layout: col=lane&15, row=(lane>>4)*4+reg (m89-verified)
    float* Ow = (float*)Dw;   // Dt dead; 2304 B >= 1536 B needed
    if (c_l < NCOMP) {
#pragma unroll
        for (int r = 0; r < 4; ++r) {
            Ow[( 0 + k4 * 4 + r) * NCOMP + c_l] = acc0[r];
            Ow[(16 + k4 * 4 + r) * NCOMP + c_l] = acc1[r];
            Ow[(32 + k4 * 4 + r) * NCOMP + c_l] = acc2[r];
            Ow[(48 + k4 * 4 + r) * NCOMP + c_l] = acc3[r];
        }
    }
    __syncthreads();
    for (int i = threadIdx.x; i < NPART; i += blockDim.x) {
        float s = ((const float*)Dsh[0])[i] + ((const float*)Dsh[1])[i]
                + ((const float*)Dsh[2])[i] + ((const float*)Dsh[3])[i];
        partials[(size_t)blockIdx.x * NPART + i] = s;
    }
}

// ---------------- reductions (atomic-free) ----------------
__global__ __launch_bounds__(NPART) void reduce1_kernel(
    const float* __restrict__ partials, float* __restrict__ partials2, int nblk)
{
    int i = threadIdx.x, j = blockIdx.x;
    float s = 0.f;
    for (int b = j; b < nblk; b += RED1_BLOCKS)
        s += partials[(size_t)b * NPART + i];
    partials2[(size_t)j * NPART + i] = s;
}

__global__ __launch_bounds__(NPART) void reduce2_kernel(
    const float* __restrict__ partials2, float* __restrict__ dst)  // dst: 64*9
{
    int i = threadIdx.x;
    float s = 0.f;
#pragma unroll
    for (int j = 0; j < RED1_BLOCKS; ++j)
        s += partials2[(size_t)j * NPART + i];
    int g = i / NCOMP, c = i % NCOMP;
    int r   = (c < 3) ? 0 : ((c < 5) ? 1 : 2);
    int col = (c < 3) ? c : ((c < 5) ? c - 2 : 2);
    dst[g * 9 + r * 3 + col] = s;
    if (r != col) dst[g * 9 + col * 3 + r] = s;
}

// ---------------- fallback (tiny ws): LDS-atomic path ----------------
__global__ void zero_out_kernel(float* __restrict__ out, int n) {
    int i = blockIdx.x * blockDim.x + threadIdx.x;
    if (i < n) out[i] = 0.f;
}

__global__ __launch_bounds__(256) void virial_atomic(
    const float* __restrict__ disp, const float* __restrict__ edge_w,
    const int* __restrict__ edge_index, const int* __restrict__ batch,
    float* __restrict__ out, int E)
{
    __shared__ float acc[NG * 7];
    for (int i = threadIdx.x; i < NG * 7; i += blockDim.x) acc[i] = 0.f;
    __syncthreads();
    int tid = blockIdx.x * blockDim.x + threadIdx.x;
    int stride = gridDim.x * blockDim.x;
    for (int e = tid; e < E; e += stride) {
        float d0 = disp[e*3], d1 = disp[e*3+1], d2 = disp[e*3+2];
        float c = -2.f * edge_w[e];
        int g0 = batch[edge_index[e]], g1 = batch[edge_index[E + e]];
        float v[6] = {c*d0*d0, c*d0*d1, c*d0*d2, c*d1*d1, c*d1*d2, c*d2*d2};
#pragma unroll
        for (int k = 0; k < 6; ++k) {
            lds_add(&acc[g0*7+k], v[k]);
            lds_add(&acc[g1*7+k], v[k]);
        }
    }
    __syncthreads();
    for (int i = threadIdx.x; i < NG * 9; i += blockDim.x) {
        int g = i / 9, ij = i % 9, r = ij / 3, cc = ij % 3;
        int lo = r < cc ? r : cc, hi = r < cc ? cc : r;
        int comp = (lo == 0) ? hi : ((lo == 1) ? 2 + hi : 5);
        __hip_atomic_fetch_add(&out[i], acc[g*7+comp], __ATOMIC_RELAXED, __HIP_MEMORY_SCOPE_AGENT);
    }
}

extern "C" void kernel_launch(void* const* d_in, const int* in_sizes, int n_in,
                              void* d_out, int out_size, void* d_ws, size_t ws_size,
                              hipStream_t stream) {
    const float* disp       = (const float*)d_in[0];
    const float* edge_w     = (const float*)d_in[1];
    const int*   edge_index = (const int*)d_in[2];
    const int*   batch      = (const int*)d_in[3];
    float*       out        = (float*)d_out;
    const int E = in_sizes[1];
    const int N = in_sizes[3];

    const size_t need = (size_t)(MFMA_BLOCKS + RED1_BLOCKS) * NPART * sizeof(float)
                        + 128 * sizeof(int);

    if (ws_size >= need) {
        float* pm = (float*)d_ws;                         // [MFMA_BLOCKS][NPART]
        float* p2 = pm + (size_t)MFMA_BLOCKS * NPART;     // [RED1_BLOCKS][NPART]
        int*   B  = (int*)(p2 + (size_t)RED1_BLOCKS * NPART);   // [65]

        bounds_init<<<1, 128, 0, stream>>>(B, N);
        bounds_min<<<256, 256, 0, stream>>>(batch, B, N);
        virial_mfma<<<MFMA_BLOCKS, 256, 0, stream>>>(disp, edge_w, edge_index, B, pm, E);
        reduce1_kernel<<<RED1_BLOCKS, NPART, 0, stream>>>(pm, p2, MFMA_BLOCKS);
        reduce2_kernel<<<1, NPART, 0, stream>>>(p2, out);
    } else {
        zero_out_kernel<<<1, 256, 0, stream>>>(out, NG * 9);
        virial_atomic<<<2048, 256, 0, stream>>>(disp, edge_w, edge_index, batch, out, E);
    }
}

// Round 21
// 39.806 us; speedup vs baseline: 1.1941x; 1.0661x over previous
//
#include <hip/hip_runtime.h>

// R21: R20 (42.4us, verified absmax 4) with the bounds machinery collapsed.
// batch is SORTED -> B[g] = lower_bound(batch, g) directly: one 65-thread
// kernel (17-step binary search, ~1-2us) replaces bounds_init + bounds_min
// (-1 launch, -400KB scan), and B is non-decreasing by construction with
// B[64]=N, so the per-block suffix-min scan is deleted as well.
// Main loop / M/Dt/MFMA body / reductions byte-identical to R20.

#define NG 64
#define NCOMP 6
#define NPART (NG * NCOMP)      // 384
#define RED1_BLOCKS 64
#define MFMA_BLOCKS 768         // 3 blocks/CU (LDS-capped)
#define WPB 4
#define MROW 72                 // 64 + 8 pad ushorts; 144B rows (16B-aligned)
#define DROW 72

typedef unsigned short u16_t;
typedef unsigned int   u32_t;
typedef __attribute__((ext_vector_type(8))) short short8;
typedef __attribute__((ext_vector_type(4))) float f32x4;

__device__ __forceinline__ u16_t f2bf(float f) {
    union { float f; u32_t u; } v; v.f = f;
    u32_t r = v.u + 0x7FFFu + ((v.u >> 16) & 1u);
    return (u16_t)(r >> 16);
}

__device__ __forceinline__ void lds_add(float* p, float v) {
    __hip_atomic_fetch_add(p, v, __ATOMIC_RELAXED, __HIP_MEMORY_SCOPE_WORKGROUP);
}

// graph(a) = max{g : Bs[g] <= a}; Bs[g] = first atom index with batch >= g
// (non-decreasing), Bs[64] = N sentinel.
__device__ __forceinline__ int gsearch(const int* Bs, int a) {
    int lo = 0;
#pragma unroll
    for (int st = 32; st >= 1; st >>= 1)
        lo += (Bs[lo + st] <= a) ? st : 0;
    return lo;
}

// ---------------- bounds table: B[g] = lower_bound(batch, g) ----------------
__global__ void bounds_build(const int* __restrict__ batch, int* __restrict__ B,
                             int N)
{
    int g = threadIdx.x;
    if (g > 64) return;
    // first index i with batch[i] >= g  (batch sorted ascending)
    int lo = 0, len = N;
    while (len > 0) {
        int half = len >> 1;
        int mid  = lo + half;
        if (batch[mid] < g) { lo = mid + 1; len -= half + 1; }
        else                { len = half; }
    }
    B[g] = lo;   // g=64: no element >= 64 -> lo = N (sentinel)
}

// ---------------- MFMA main kernel ----------------
__global__ __launch_bounds__(256) void virial_mfma(
    const float* __restrict__ disp, const float* __restrict__ edge_w,
    const int* __restrict__ edge_index, const int* __restrict__ Bg,
    float* __restrict__ partials, int E)
{
    __shared__ u16_t Msh[WPB][NG * MROW];   // 36864 B
    __shared__ u16_t Dsh[WPB][16 * DROW];   //  9216 B (rows 6..15 stay zero;
                                            //  reused as per-wave f32 stage)
    __shared__ int   Bs[65];                //   260 B graph-boundary table

    const int lane = threadIdx.x & 63;
    const int wave = threadIdx.x >> 6;
    u16_t* Mw = Msh[wave];
    u16_t* Dw = Dsh[wave];

    if (threadIdx.x < 65) Bs[threadIdx.x] = Bg[threadIdx.x];
    {   // zero per-wave M and Dt (same-wave DS ops are in order)
        u32_t* p = (u32_t*)Mw;
        for (int i = lane; i < NG * MROW / 2; i += 64) p[i] = 0u;
        u32_t* q = (u32_t*)Dw;
        for (int i = lane; i < 16 * DROW / 2; i += 64) q[i] = 0u;
    }
    __syncthreads();   // Bs ready (already non-decreasing; read-only below)

    f32x4 acc0 = {0,0,0,0}, acc1 = {0,0,0,0}, acc2 = {0,0,0,0}, acc3 = {0,0,0,0};
    const int ngroups = (E + 63) >> 6;
    const int gstride = (int)gridDim.x * WPB;
    const int c_l = lane & 15;
    const int k4  = lane >> 4;
    int pg0 = 0, pg1 = 0;

    int grp = (int)blockIdx.x * WPB + wave;

    // 1-deep prefetch of the STREAMING loads (w, disp, idx) — no gathers
    float pw = 0.f, px = 0.f, py = 0.f, pz = 0.f;
    int   ps = 0, pt = 0;
    if (grp < ngroups) {
        int e  = grp * 64 + lane;
        int ec = e < E ? e : E - 1;
        pw = (e < E) ? edge_w[ec] : 0.f;   // w=0 kills clamped-tail terms
        px = disp[ec * 3 + 0];
        py = disp[ec * 3 + 1];
        pz = disp[ec * 3 + 2];
        ps = edge_index[ec];
        pt = edge_index[E + ec];
    }

    while (grp < ngroups) {
        const float w = pw, d0 = px, d1 = py, d2 = pz;
        const int   sC = ps, tC = pt;

        const int nxt = grp + gstride;
        if (nxt < ngroups) {
            int e  = nxt * 64 + lane;
            int ec = e < E ? e : E - 1;
            pw = (e < E) ? edge_w[ec] : 0.f;
            px = disp[ec * 3 + 0];
            py = disp[ec * 3 + 1];
            pz = disp[ec * 3 + 2];
            ps = edge_index[ec];
            pt = edge_index[E + ec];
        }

        // gather-free endpoint->graph: 6-step ladder over LDS table
        const int g0 = gsearch(Bs, sC);
        const int g1 = gsearch(Bs, tC);

        // --- R10-verified body ---
        Mw[pg0 * MROW + lane] = 0;
        Mw[pg1 * MROW + lane] = 0;
        Mw[g0 * MROW + lane] = 0x3F80u;                          // 1.0
        Mw[g1 * MROW + lane] = (g1 == g0) ? 0x4000u : 0x3F80u;   // 2.0 / 1.0
        pg0 = g0; pg1 = g1;

        float cw = -2.f * w;
        Dw[0 * DROW + lane] = f2bf(cw * d0 * d0);
        Dw[1 * DROW + lane] = f2bf(cw * d0 * d1);
        Dw[2 * DROW + lane] = f2bf(cw * d0 * d2);
        Dw[3 * DROW + lane] = f2bf(cw * d1 * d1);
        Dw[4 * DROW + lane] = f2bf(cw * d1 * d2);
        Dw[5 * DROW + lane] = f2bf(cw * d2 * d2);

#pragma unroll
        for (int half = 0; half < 2; ++half) {
            const int kb = half * 32 + k4 * 8;
            short8 bf = *(const short8*)&Dw[c_l * DROW + kb];
            short8 a0 = *(const short8*)&Mw[( 0 + c_l) * MROW + kb];
            short8 a1 = *(const short8*)&Mw[(16 + c_l) * MROW + kb];
            short8 a2 = *(const short8*)&Mw[(32 + c_l) * MROW + kb];
            short8 a3 = *(const short8*)&Mw[(48 + c_l) * MROW + kb];
            acc0 = __builtin_amdgcn_mfma_f32_16x16x32_bf16(a0, bf, acc0, 0, 0, 0);
            acc1 = __builtin_amdgcn_mfma_f32_16x16x32_bf16(a1, bf, acc1, 0, 0, 0);
            acc2 = __builtin_amdgcn_mfma_f32_16x16x32_bf16(a2, bf, acc2, 0, 0, 0);
            acc3 = __builtin_amdgcn_mfma_f32_16x16x32_bf16(a3, bf, acc3, 0, 0, 0);
        }

        grp = nxt;
    }

    // C/D layout: col=lane&15, row=(lane>>4)*4+reg (m89-verified)
    float* Ow = (float*)Dw;   // Dt dead; 2304 B >= 1536 B needed
    if (c_l < NCOMP) {
#pragma unroll
        for (int r = 0; r < 4; ++r) {
            Ow[( 0 + k4 * 4 + r) * NCOMP + c_l] = acc0[r];
            Ow[(16 + k4 * 4 + r) * NCOMP + c_l] = acc1[r];
            Ow[(32 + k4 * 4 + r) * NCOMP + c_l] = acc2[r];
            Ow[(48 + k4 * 4 + r) * NCOMP + c_l] = acc3[r];
        }
    }
    __syncthreads();
    for (int i = threadIdx.x; i < NPART; i += blockDim.x) {
        float s = ((const float*)Dsh[0])[i] + ((const float*)Dsh[1])[i]
                + ((const float*)Dsh[2])[i] + ((const float*)Dsh[3])[i];
        partials[(size_t)blockIdx.x * NPART + i] = s;
    }
}

// ---------------- reductions (atomic-free) ----------------
__global__ __launch_bounds__(NPART) void reduce1_kernel(
    const float* __restrict__ partials, float* __restrict__ partials2, int nblk)
{
    int i = threadIdx.x, j = blockIdx.x;
    float s = 0.f;
    for (int b = j; b < nblk; b += RED1_BLOCKS)
        s += partials[(size_t)b * NPART + i];
    partials2[(size_t)j * NPART + i] = s;
}

__global__ __launch_bounds__(NPART) void reduce2_kernel(
    const float* __restrict__ partials2, float* __restrict__ dst)  // dst: 64*9
{
    int i = threadIdx.x;
    float s = 0.f;
#pragma unroll
    for (int j = 0; j < RED1_BLOCKS; ++j)
        s += partials2[(size_t)j * NPART + i];
    int g = i / NCOMP, c = i % NCOMP;
    int r   = (c < 3) ? 0 : ((c < 5) ? 1 : 2);
    int col = (c < 3) ? c : ((c < 5) ? c - 2 : 2);
    dst[g * 9 + r * 3 + col] = s;
    if (r != col) dst[g * 9 + col * 3 + r] = s;
}

// ---------------- fallback (tiny ws): LDS-atomic path ----------------
__global__ void zero_out_kernel(float* __restrict__ out, int n) {
    int i = blockIdx.x * blockDim.x + threadIdx.x;
    if (i < n) out[i] = 0.f;
}

__global__ __launch_bounds__(256) void virial_atomic(
    const float* __restrict__ disp, const float* __restrict__ edge_w,
    const int* __restrict__ edge_index, const int* __restrict__ batch,
    float* __restrict__ out, int E)
{
    __shared__ float acc[NG * 7];
    for (int i = threadIdx.x; i < NG * 7; i += blockDim.x) acc[i] = 0.f;
    __syncthreads();
    int tid = blockIdx.x * blockDim.x + threadIdx.x;
    int stride = gridDim.x * blockDim.x;
    for (int e = tid; e < E; e += stride) {
        float d0 = disp[e*3], d1 = disp[e*3+1], d2 = disp[e*3+2];
        float c = -2.f * edge_w[e];
        int g0 = batch[edge_index[e]], g1 = batch[edge_index[E + e]];
        float v[6] = {c*d0*d0, c*d0*d1, c*d0*d2, c*d1*d1, c*d1*d2, c*d2*d2};
#pragma unroll
        for (int k = 0; k < 6; ++k) {
            lds_add(&acc[g0*7+k], v[k]);
            lds_add(&acc[g1*7+k], v[k]);
        }
    }
    __syncthreads();
    for (int i = threadIdx.x; i < NG * 9; i += blockDim.x) {
        int g = i / 9, ij = i % 9, r = ij / 3, cc = ij % 3;
        int lo = r < cc ? r : cc, hi = r < cc ? cc : r;
        int comp = (lo == 0) ? hi : ((lo == 1) ? 2 + hi : 5);
        __hip_atomic_fetch_add(&out[i], acc[g*7+comp], __ATOMIC_RELAXED, __HIP_MEMORY_SCOPE_AGENT);
    }
}

extern "C" void kernel_launch(void* const* d_in, const int* in_sizes, int n_in,
                              void* d_out, int out_size, void* d_ws, size_t ws_size,
                              hipStream_t stream) {
    const float* disp       = (const float*)d_in[0];
    const float* edge_w     = (const float*)d_in[1];
    const int*   edge_index = (const int*)d_in[2];
    const int*   batch      = (const int*)d_in[3];
    float*       out        = (float*)d_out;
    const int E = in_sizes[1];
    const int N = in_sizes[3];

    const size_t need = (size_t)(MFMA_BLOCKS + RED1_BLOCKS) * NPART * sizeof(float)
                        + 128 * sizeof(int);

    if (ws_size >= need) {
        float* pm = (float*)d_ws;                         // [MFMA_BLOCKS][NPART]
        float* p2 = pm + (size_t)MFMA_BLOCKS * NPART;     // [RED1_BLOCKS][NPART]
        int*   B  = (int*)(p2 + (size_t)RED1_BLOCKS * NPART);   // [65]

        bounds_build<<<1, 128, 0, stream>>>(batch, B, N);
        virial_mfma<<<MFMA_BLOCKS, 256, 0, stream>>>(disp, edge_w, edge_index, B, pm, E);
        reduce1_kernel<<<RED1_BLOCKS, NPART, 0, stream>>>(pm, p2, MFMA_BLOCKS);
        reduce2_kernel<<<1, NPART, 0, stream>>>(p2, out);
    } else {
        zero_out_kernel<<<1, 256, 0, stream>>>(out, NG * 9);
        virial_atomic<<<2048, 256, 0, stream>>>(disp, edge_w, edge_index, batch, out, E);
    }
}

// Round 22
// 39.342 us; speedup vs baseline: 1.2081x; 1.0118x over previous
//
#include <hip/hip_runtime.h>

// R22: R21 (39.8us, verified absmax 4) + LDS diet -> 4 blocks/CU.
//  (a) Dt shrinks 16->6 rows: B-fragment lanes c_l>=6 clamp to row 5; their
//      products land in C cols 6..15 which the epilogue DISCARDS (c_l<6
//      filter) -> numerics of kept outputs unchanged.
//  (b) f32 output staging moves Dsh->Msh (M dead after main loop).
// LDS 46.3KB -> 40.6KB (<40.96KB) -> 4 blocks/CU = 16 waves (was 12).
// Grid 768 -> 1024. Everything else byte-identical to R21.

#define NG 64
#define NCOMP 6
#define NPART (NG * NCOMP)      // 384
#define RED1_BLOCKS 64
#define MFMA_BLOCKS 1024        // 4 blocks/CU
#define WPB 4
#define MROW 72                 // 64 + 8 pad ushorts; 144B rows (16B-aligned)
#define DROW 72
#define DTROWS 6                // only rows 0..5 are real (cols 6..15 of C discarded)

typedef unsigned short u16_t;
typedef unsigned int   u32_t;
typedef __attribute__((ext_vector_type(8))) short short8;
typedef __attribute__((ext_vector_type(4))) float f32x4;

__device__ __forceinline__ u16_t f2bf(float f) {
    union { float f; u32_t u; } v; v.f = f;
    u32_t r = v.u + 0x7FFFu + ((v.u >> 16) & 1u);
    return (u16_t)(r >> 16);
}

__device__ __forceinline__ void lds_add(float* p, float v) {
    __hip_atomic_fetch_add(p, v, __ATOMIC_RELAXED, __HIP_MEMORY_SCOPE_WORKGROUP);
}

// graph(a) = max{g : Bs[g] <= a}; Bs non-decreasing, Bs[64] = N sentinel.
__device__ __forceinline__ int gsearch(const int* Bs, int a) {
    int lo = 0;
#pragma unroll
    for (int st = 32; st >= 1; st >>= 1)
        lo += (Bs[lo + st] <= a) ? st : 0;
    return lo;
}

// ---------------- bounds table: B[g] = lower_bound(batch, g) ----------------
__global__ void bounds_build(const int* __restrict__ batch, int* __restrict__ B,
                             int N)
{
    int g = threadIdx.x;
    if (g > 64) return;
    int lo = 0, len = N;
    while (len > 0) {
        int half = len >> 1;
        int mid  = lo + half;
        if (batch[mid] < g) { lo = mid + 1; len -= half + 1; }
        else                { len = half; }
    }
    B[g] = lo;   // g=64 -> N (sentinel)
}

// ---------------- MFMA main kernel ----------------
__global__ __launch_bounds__(256) void virial_mfma(
    const float* __restrict__ disp, const float* __restrict__ edge_w,
    const int* __restrict__ edge_index, const int* __restrict__ Bg,
    float* __restrict__ partials, int E)
{
    __shared__ u16_t Msh[WPB][NG * MROW];      // 36864 B (reused as f32 stage)
    __shared__ u16_t Dsh[WPB][DTROWS * DROW];  //  3456 B (6 real rows only)
    __shared__ int   Bs[65];                   //   260 B

    const int lane = threadIdx.x & 63;
    const int wave = threadIdx.x >> 6;
    u16_t* Mw = Msh[wave];
    u16_t* Dw = Dsh[wave];

    if (threadIdx.x < 65) Bs[threadIdx.x] = Bg[threadIdx.x];
    {   // zero per-wave M and Dt (same-wave DS ops are in order)
        u32_t* p = (u32_t*)Mw;
        for (int i = lane; i < NG * MROW / 2; i += 64) p[i] = 0u;
        u32_t* q = (u32_t*)Dw;
        for (int i = lane; i < DTROWS * DROW / 2; i += 64) q[i] = 0u;
    }
    __syncthreads();   // Bs ready

    f32x4 acc0 = {0,0,0,0}, acc1 = {0,0,0,0}, acc2 = {0,0,0,0}, acc3 = {0,0,0,0};
    const int ngroups = (E + 63) >> 6;
    const int gstride = (int)gridDim.x * WPB;
    const int c_l = lane & 15;
    const int k4  = lane >> 4;
    const int drow = (c_l < DTROWS) ? c_l : (DTROWS - 1);  // clamp: junk -> discarded C cols
    int pg0 = 0, pg1 = 0;

    int grp = (int)blockIdx.x * WPB + wave;

    // 1-deep prefetch of the streaming loads (w, disp, idx) — no gathers
    float pw = 0.f, px = 0.f, py = 0.f, pz = 0.f;
    int   ps = 0, pt = 0;
    if (grp < ngroups) {
        int e  = grp * 64 + lane;
        int ec = e < E ? e : E - 1;
        pw = (e < E) ? edge_w[ec] : 0.f;   // w=0 kills clamped-tail terms
        px = disp[ec * 3 + 0];
        py = disp[ec * 3 + 1];
        pz = disp[ec * 3 + 2];
        ps = edge_index[ec];
        pt = edge_index[E + ec];
    }

    while (grp < ngroups) {
        const float w = pw, d0 = px, d1 = py, d2 = pz;
        const int   sC = ps, tC = pt;

        const int nxt = grp + gstride;
        if (nxt < ngroups) {
            int e  = nxt * 64 + lane;
            int ec = e < E ? e : E - 1;
            pw = (e < E) ? edge_w[ec] : 0.f;
            px = disp[ec * 3 + 0];
            py = disp[ec * 3 + 1];
            pz = disp[ec * 3 + 2];
            ps = edge_index[ec];
            pt = edge_index[E + ec];
        }

        // gather-free endpoint->graph: 6-step ladder over LDS table
        const int g0 = gsearch(Bs, sC);
        const int g1 = gsearch(Bs, tC);

        // --- R10-verified body ---
        Mw[pg0 * MROW + lane] = 0;
        Mw[pg1 * MROW + lane] = 0;
        Mw[g0 * MROW + lane] = 0x3F80u;                          // 1.0
        Mw[g1 * MROW + lane] = (g1 == g0) ? 0x4000u : 0x3F80u;   // 2.0 / 1.0
        pg0 = g0; pg1 = g1;

        float cw = -2.f * w;
        Dw[0 * DROW + lane] = f2bf(cw * d0 * d0);
        Dw[1 * DROW + lane] = f2bf(cw * d0 * d1);
        Dw[2 * DROW + lane] = f2bf(cw * d0 * d2);
        Dw[3 * DROW + lane] = f2bf(cw * d1 * d1);
        Dw[4 * DROW + lane] = f2bf(cw * d1 * d2);
        Dw[5 * DROW + lane] = f2bf(cw * d2 * d2);

#pragma unroll
        for (int half = 0; half < 2; ++half) {
            const int kb = half * 32 + k4 * 8;
            short8 bf = *(const short8*)&Dw[drow * DROW + kb];
            short8 a0 = *(const short8*)&Mw[( 0 + c_l) * MROW + kb];
            short8 a1 = *(const short8*)&Mw[(16 + c_l) * MROW + kb];
            short8 a2 = *(const short8*)&Mw[(32 + c_l) * MROW + kb];
            short8 a3 = *(const short8*)&Mw[(48 + c_l) * MROW + kb];
            acc0 = __builtin_amdgcn_mfma_f32_16x16x32_bf16(a0, bf, acc0, 0, 0, 0);
            acc1 = __builtin_amdgcn_mfma_f32_16x16x32_bf16(a1, bf, acc1, 0, 0, 0);
            acc2 = __builtin_amdgcn_mfma_f32_16x16x32_bf16(a2, bf, acc2, 0, 0, 0);
            acc3 = __builtin_amdgcn_mfma_f32_16x16x32_bf16(a3, bf, acc3, 0, 0, 0);
        }

        grp = nxt;
    }

    // C/D layout: col=lane&15, row=(lane>>4)*4+reg (m89-verified).
    // Stage per-wave f32 partial into this wave's (now dead) M region.
    __syncthreads();
    float* Ow = (float*)Mw;   // 9216 B >= 1536 B needed
    if (c_l < NCOMP) {
#pragma unroll
        for (int r = 0; r < 4; ++r) {
            Ow[( 0 + k4 * 4 + r) * NCOMP + c_l] = acc0[r];
            Ow[(16 + k4 * 4 + r) * NCOMP + c_l] = acc1[r];
            Ow[(32 + k4 * 4 + r) * NCOMP + c_l] = acc2[r];
            Ow[(48 + k4 * 4 + r) * NCOMP + c_l] = acc3[r];
        }
    }
    __syncthreads();
    for (int i = threadIdx.x; i < NPART; i += blockDim.x) {
        float s = ((const float*)Msh[0])[i] + ((const float*)Msh[1])[i]
                + ((const float*)Msh[2])[i] + ((const float*)Msh[3])[i];
        partials[(size_t)blockIdx.x * NPART + i] = s;
    }
}

// ---------------- reductions (atomic-free) ----------------
__global__ __launch_bounds__(NPART) void reduce1_kernel(
    const float* __restrict__ partials, float* __restrict__ partials2, int nblk)
{
    int i = threadIdx.x, j = blockIdx.x;
    float s = 0.f;
    for (int b = j; b < nblk; b += RED1_BLOCKS)
        s += partials[(size_t)b * NPART + i];
    partials2[(size_t)j * NPART + i] = s;
}

__global__ __launch_bounds__(NPART) void reduce2_kernel(
    const float* __restrict__ partials2, float* __restrict__ dst)  // dst: 64*9
{
    int i = threadIdx.x;
    float s = 0.f;
#pragma unroll
    for (int j = 0; j < RED1_BLOCKS; ++j)
        s += partials2[(size_t)j * NPART + i];
    int g = i / NCOMP, c = i % NCOMP;
    int r   = (c < 3) ? 0 : ((c < 5) ? 1 : 2);
    int col = (c < 3) ? c : ((c < 5) ? c - 2 : 2);
    dst[g * 9 + r * 3 + col] = s;
    if (r != col) dst[g * 9 + col * 3 + r] = s;
}

// ---------------- fallback (tiny ws): LDS-atomic path ----------------
__global__ void zero_out_kernel(float* __restrict__ out, int n) {
    int i = blockIdx.x * blockDim.x + threadIdx.x;
    if (i < n) out[i] = 0.f;
}

__global__ __launch_bounds__(256) void virial_atomic(
    const float* __restrict__ disp, const float* __restrict__ edge_w,
    const int* __restrict__ edge_index, const int* __restrict__ batch,
    float* __restrict__ out, int E)
{
    __shared__ float acc[NG * 7];
    for (int i = threadIdx.x; i < NG * 7; i += blockDim.x) acc[i] = 0.f;
    __syncthreads();
    int tid = blockIdx.x * blockDim.x + threadIdx.x;
    int stride = gridDim.x * blockDim.x;
    for (int e = tid; e < E; e += stride) {
        float d0 = disp[e*3], d1 = disp[e*3+1], d2 = disp[e*3+2];
        float c = -2.f * edge_w[e];
        int g0 = batch[edge_index[e]], g1 = batch[edge_index[E + e]];
        float v[6] = {c*d0*d0, c*d0*d1, c*d0*d2, c*d1*d1, c*d1*d2, c*d2*d2};
#pragma unroll
        for (int k = 0; k < 6; ++k) {
            lds_add(&acc[g0*7+k], v[k]);
            lds_add(&acc[g1*7+k], v[k]);
        }
    }
    __syncthreads();
    for (int i = threadIdx.x; i < NG * 9; i += blockDim.x) {
        int g = i / 9, ij = i % 9, r = ij / 3, cc = ij % 3;
        int lo = r < cc ? r : cc, hi = r < cc ? cc : r;
        int comp = (lo == 0) ? hi : ((lo == 1) ? 2 + hi : 5);
        __hip_atomic_fetch_add(&out[i], acc[g*7+comp], __ATOMIC_RELAXED, __HIP_MEMORY_SCOPE_AGENT);
    }
}

extern "C" void kernel_launch(void* const* d_in, const int* in_sizes, int n_in,
                              void* d_out, int out_size, void* d_ws, size_t ws_size,
                              hipStream_t stream) {
    const float* disp       = (const float*)d_in[0];
    const float* edge_w     = (const float*)d_in[1];
    const int*   edge_index = (const int*)d_in[2];
    const int*   batch      = (const int*)d_in[3];
    float*       out        = (float*)d_out;
    const int E = in_sizes[1];
    const int N = in_sizes[3];

    const size_t need = (size_t)(MFMA_BLOCKS + RED1_BLOCKS) * NPART * sizeof(float)
                        + 128 * sizeof(int);

    if (ws_size >= need) {
        float* pm = (float*)d_ws;                         // [MFMA_BLOCKS][NPART]
        float* p2 = pm + (size_t)MFMA_BLOCKS * NPART;     // [RED1_BLOCKS][NPART]
        int*   B  = (int*)(p2 + (size_t)RED1_BLOCKS * NPART);   // [65]

        bounds_build<<<1, 128, 0, stream>>>(batch, B, N);
        virial_mfma<<<MFMA_BLOCKS, 256, 0, stream>>>(disp, edge_w, edge_index, B, pm, E);
        reduce1_kernel<<<RED1_BLOCKS, NPART, 0, stream>>>(pm, p2, MFMA_BLOCKS);
        reduce2_kernel<<<1, NPART, 0, stream>>>(p2, out);
    } else {
        zero_out_kernel<<<1, 256, 0, stream>>>(out, NG * 9);
        virial_atomic<<<2048, 256, 0, stream>>>(disp, edge_w, edge_index, batch, out, E);
    }
}